// Round 2
// baseline (1372.682 us; speedup 1.0000x reference)
//
#include <hip/hip_runtime.h>
#include <hip/hip_bf16.h>
#include <math.h>

// Problem constants
#define BB 64
#define LL 200
#define NQ 1024
#define DD 256
#define HH 512
#define QQ 1024
#define G3 1536   // 3*H
#define BL 12800  // B*L
#define GBLK 256  // persistent GRU grid: 1 block/CU, all CUs active
#define NBG 16    // batch groups (4 batches each)
#define NUG 16    // unit groups (32 units each)

// ---------------- workspace layout (in floats) ----------------
#define OFF_ACC   ((size_t)0)                    // [0]=creg_raw [1]=mse [2]=maskcnt
#define OFF_CELLS ((size_t)16)                   // (unused now)
#define OFF_HA    ((size_t)1056)                 // (unused now; hU aliases OFF_AQ)
#define OFF_AQ    (OFF_HA + 65536)               // 1025*1536  (dead after xgt -> reused as hU+sent)
#define OFF_DQ    (OFF_AQ + 1574400)
#define OFF_BQA   (OFF_DQ + 1574400)             // 2*1536
#define OFF_CQA   (OFF_BQA + 3072)
#define OFF_WSUM  (OFF_CQA + 3072)               // 1536*256
#define OFF_FCWT  (OFF_WSUM + 393216)            // 512*1024
#define OFF_M2    (OFF_FCWT + 524288)            // 1024*512
#define OFF_MB    (OFF_M2 + 524288)              // 1024
#define OFF_XG    (OFF_MB + 1024)                // xgP [16][200][1536][4] (also temp M2 splitk parts)
#define OFF_GRUT  (OFF_XG + 19660800)            // [t][b][k]
#define OFF_QINT  (OFF_GRUT + 6553600)           // 12800 ints [B][L]
#define OFF_QAINT (OFF_QINT + 12800)
#define OFF_PIDF  (OFF_QAINT + 12800)
#define OFF_MVAL  (OFF_PIDF + 12800)
#define OFF_MC    (OFF_MVAL + 12800)
#define OFF_MI    (OFF_MC + 12800)
#define OFF_NMC   (OFF_MI + 12800)
#define OFF_AA    (OFF_NMC + 12800)
#define OFF_PREDS (OFF_AA + 12800)

typedef float f32x4 __attribute__((ext_vector_type(4)));

__device__ __forceinline__ float wave_sum64(float v) {
    #pragma unroll
    for (int o = 32; o > 0; o >>= 1) v += __shfl_down(v, o, 64);
    return v;
}

// LLC-coherent (bypass L1/L2) ops
__device__ __forceinline__ f32x4 llc_load4w(const float* p) {
    f32x4 v;
    asm volatile("global_load_dwordx4 %0, %1, off sc0 sc1\n\ts_waitcnt vmcnt(0)"
                 : "=&v"(v) : "v"(p));
    return v;
}
__device__ __forceinline__ void llc_load2s(const float* p0, const float* p1,
                                           float& a, float& b) {
    asm volatile("global_load_dword %0, %2, off sc0 sc1\n\t"
                 "global_load_dword %1, %3, off sc0 sc1\n\t"
                 "s_waitcnt vmcnt(0)"
                 : "=&v"(a), "=&v"(b) : "v"(p0), "v"(p1));
}
__device__ __forceinline__ void llc_store1(float* p, float v) {
    asm volatile("global_store_dword %0, %1, off sc0 sc1" :: "v"(p), "v"(v) : "memory");
}

// quad (4-lane) butterfly sum via DPP quad_perm (VALU pipe, not LDS)
__device__ __forceinline__ float quad_sum(float v) {
    float t1 = __int_as_float(__builtin_amdgcn_update_dpp(
        0, __float_as_int(v), 0xB1, 0xF, 0xF, true));   // quad_perm xor1
    v += t1;
    float t2 = __int_as_float(__builtin_amdgcn_update_dpp(
        0, __float_as_int(v), 0x4E, 0xF, 0xF, true));   // quad_perm xor2
    return v + t2;
}

// -------- meta: q, qa, pid per (b,t); c_reg accumulation --------
__global__ __launch_bounds__(256) void prep_meta(
    const int* __restrict__ q_data, const int* __restrict__ qa_data,
    const int* __restrict__ pid_data, const float* __restrict__ diff_parm,
    int* __restrict__ qint, int* __restrict__ qaint, float* __restrict__ pidf,
    float* __restrict__ acc)
{
    int r = blockIdx.x * 256 + threadIdx.x;
    float pp = 0.f;
    if (r < BL) {
        int q = q_data[r];
        qint[r] = q;
        qaint[r] = (qa_data[r] - q) / NQ;
        float pid = diff_parm[pid_data[r]];
        pidf[r] = pid;
        pp = pid * pid;
    }
    pp = wave_sum64(pp);
    __shared__ float sm[4];
    int lane = threadIdx.x & 63, w = threadIdx.x >> 6;
    if (lane == 0) sm[w] = pp;
    __syncthreads();
    if (threadIdx.x == 0) atomicAdd(&acc[0], sm[0] + sm[1] + sm[2] + sm[3]);
}

// -------- wsum[g,d] = w_ih[g,d] + w_ih[g,256+d] --------
__global__ __launch_bounds__(256) void wsum_kernel(const float* __restrict__ w_ih,
                                                   float* __restrict__ wsum)
{
    int g = blockIdx.x, d = threadIdx.x;
    wsum[(size_t)g * DD + d] = w_ih[(size_t)g * 2 * DD + d] + w_ih[(size_t)g * 2 * DD + DD + d];
}

// -------- transpose [R,C] -> [C,R] --------
__global__ __launch_bounds__(256) void transpose_kernel(const float* __restrict__ in,
                                                        float* __restrict__ out, int R, int C)
{
    __shared__ float tile[32][33];
    int r0 = blockIdx.y * 32, c0 = blockIdx.x * 32;
    int tx = threadIdx.x & 31, ty = threadIdx.x >> 5;
    #pragma unroll
    for (int i = 0; i < 32; i += 8) {
        int r = r0 + ty + i, c = c0 + tx;
        if (r < R && c < C) tile[ty + i][tx] = in[(size_t)r * C + c];
    }
    __syncthreads();
    #pragma unroll
    for (int i = 0; i < 32; i += 8) {
        int c = c0 + ty + i, r = r0 + tx;
        if (c < C && r < R) out[(size_t)c * R + r] = tile[tx][ty + i];
    }
}

// -------- dual-batched NT GEMM (two independent problems, z picks) --------
__global__ __launch_bounds__(256) void gemm_nt_dual(
    const float* __restrict__ A0, const float* __restrict__ A1, int lda,
    const float* __restrict__ B0, const float* __restrict__ B1, int ldb0, int ldb1,
    float* __restrict__ C0, float* __restrict__ C1, int ldc,
    int M, int N, int K,
    const float* __restrict__ bias0, const float* __restrict__ bias1)
{
    const int z = blockIdx.z;
    const float* A = z ? A1 : A0;
    const float* B = z ? B1 : B0;
    float* C = z ? C1 : C0;
    const int ldb = z ? ldb1 : ldb0;
    const float* bias = z ? bias1 : bias0;

    __shared__ float As[16][65];
    __shared__ float Bs[16][65];
    const int bm = blockIdx.y * 64, bn = blockIdx.x * 64;
    const int tid = threadIdx.x;
    const int tx = tid & 15, ty = tid >> 4;
    const int mm = tid >> 4, kk = tid & 15;
    float acc[4][4] = {};
    float ar[4], br[4];
    #pragma unroll
    for (int i = 0; i < 4; ++i) {
        int m = bm + mm + 16 * i;
        ar[i] = (m < M) ? A[(size_t)m * lda + kk] : 0.f;
        int n = bn + mm + 16 * i;
        br[i] = (n < N) ? B[(size_t)n * ldb + kk] : 0.f;
    }
    for (int k0 = 0; k0 < K; k0 += 16) {
        #pragma unroll
        for (int i = 0; i < 4; ++i) { As[kk][mm + 16 * i] = ar[i]; Bs[kk][mm + 16 * i] = br[i]; }
        __syncthreads();
        int kn = k0 + 16;
        if (kn < K) {
            #pragma unroll
            for (int i = 0; i < 4; ++i) {
                int m = bm + mm + 16 * i;
                ar[i] = (m < M) ? A[(size_t)m * lda + kn + kk] : 0.f;
                int n = bn + mm + 16 * i;
                br[i] = (n < N) ? B[(size_t)n * ldb + kn + kk] : 0.f;
            }
        }
        #pragma unroll
        for (int kq = 0; kq < 16; ++kq) {
            float a[4], b[4];
            #pragma unroll
            for (int i = 0; i < 4; ++i) a[i] = As[kq][ty * 4 + i];
            #pragma unroll
            for (int j = 0; j < 4; ++j) b[j] = Bs[kq][tx * 4 + j];
            #pragma unroll
            for (int i = 0; i < 4; ++i)
                #pragma unroll
                for (int j = 0; j < 4; ++j) acc[i][j] += a[i] * b[j];
        }
        __syncthreads();
    }
    #pragma unroll
    for (int i = 0; i < 4; ++i) {
        int m = bm + ty * 4 + i;
        if (m >= M) continue;
        #pragma unroll
        for (int j = 0; j < 4; ++j) {
            int n = bn + tx * 4 + j;
            if (n >= N) continue;
            C[(size_t)m * ldc + n] = acc[i][j] + (bias ? bias[n] : 0.f);
        }
    }
}

// -------- split-K NT GEMM: Cp[z] = A[:, zK4:(z+1)K4] . B[:, same]^T --------
__global__ __launch_bounds__(256) void gemm_nt_splitk(
    const float* __restrict__ Ain, int lda,
    const float* __restrict__ Bin, int ldb,
    float* __restrict__ Cp, int ldc,
    int M, int N, int K4)
{
    const int z = blockIdx.z;
    const float* A = Ain + (size_t)z * K4;
    const float* B = Bin + (size_t)z * K4;
    float* C = Cp + (size_t)z * M * ldc;

    __shared__ float As[16][65];
    __shared__ float Bs[16][65];
    const int bm = blockIdx.y * 64, bn = blockIdx.x * 64;
    const int tid = threadIdx.x;
    const int tx = tid & 15, ty = tid >> 4;
    const int mm = tid >> 4, kk = tid & 15;
    float acc[4][4] = {};
    float ar[4], br[4];
    #pragma unroll
    for (int i = 0; i < 4; ++i) {
        int m = bm + mm + 16 * i;
        ar[i] = (m < M) ? A[(size_t)m * lda + kk] : 0.f;
        int n = bn + mm + 16 * i;
        br[i] = (n < N) ? B[(size_t)n * ldb + kk] : 0.f;
    }
    for (int k0 = 0; k0 < K4; k0 += 16) {
        #pragma unroll
        for (int i = 0; i < 4; ++i) { As[kk][mm + 16 * i] = ar[i]; Bs[kk][mm + 16 * i] = br[i]; }
        __syncthreads();
        int kn = k0 + 16;
        if (kn < K4) {
            #pragma unroll
            for (int i = 0; i < 4; ++i) {
                int m = bm + mm + 16 * i;
                ar[i] = (m < M) ? A[(size_t)m * lda + kn + kk] : 0.f;
                int n = bn + mm + 16 * i;
                br[i] = (n < N) ? B[(size_t)n * ldb + kn + kk] : 0.f;
            }
        }
        #pragma unroll
        for (int kq = 0; kq < 16; ++kq) {
            float a[4], b[4];
            #pragma unroll
            for (int i = 0; i < 4; ++i) a[i] = As[kq][ty * 4 + i];
            #pragma unroll
            for (int j = 0; j < 4; ++j) b[j] = Bs[kq][tx * 4 + j];
            #pragma unroll
            for (int i = 0; i < 4; ++i)
                #pragma unroll
                for (int j = 0; j < 4; ++j) acc[i][j] += a[i] * b[j];
        }
        __syncthreads();
    }
    #pragma unroll
    for (int i = 0; i < 4; ++i) {
        int m = bm + ty * 4 + i;
        if (m >= M) continue;
        #pragma unroll
        for (int j = 0; j < 4; ++j) {
            int n = bn + tx * 4 + j;
            if (n >= N) continue;
            C[(size_t)m * ldc + n] = acc[i][j];
        }
    }
}

__global__ __launch_bounds__(256) void reduce4_kernel(const float* __restrict__ p,
                                                      float* __restrict__ o, int n)
{
    int i = blockIdx.x * 256 + threadIdx.x;
    if (i < n) o[i] = p[i] + p[n + i] + p[2 * n + i] + p[3 * n + i];
}

// -------- mb[k] = sum_q matrix[k,q]*fc_b[q] --------
__global__ __launch_bounds__(256) void mb_kernel(const float* __restrict__ matrix,
                                                 const float* __restrict__ fc_b,
                                                 float* __restrict__ mb)
{
    int k = blockIdx.x;
    float s = 0.f;
    for (int q = threadIdx.x; q < QQ; q += 256) s += matrix[(size_t)k * QQ + q] * fc_b[q];
    s = wave_sum64(s);
    __shared__ float sm[4];
    int lane = threadIdx.x & 63, w = threadIdx.x >> 6;
    if (lane == 0) sm[w] = s;
    __syncthreads();
    if (threadIdx.x == 0) mb[k] = sm[0] + sm[1] + sm[2] + sm[3];
}

// -------- fused xg gather + transpose into xgP[bg][t][g][4] --------
__global__ __launch_bounds__(512) void xgt_kernel(
    const float* __restrict__ Aq, const float* __restrict__ Bqa,
    const float* __restrict__ Cqa, const float* __restrict__ Dq,
    const int* __restrict__ qint, const int* __restrict__ qaint,
    const float* __restrict__ pidf, float* __restrict__ xgP)
{
    const int t = blockIdx.x;
    __shared__ float tile[64][136];   // pad 136: 2-way max on both phases
    __shared__ int qs[BB];
    __shared__ int qas[BB];
    __shared__ float ps[BB];
    const int tid = threadIdx.x;
    if (tid < BB) {
        qs[tid] = qint[tid * LL + t];
        qas[tid] = qaint[tid * LL + t];
        ps[tid] = pidf[tid * LL + t];
    }
    __syncthreads();
    for (int g0 = 0; g0 < G3; g0 += 128) {
        #pragma unroll
        for (int it = 0; it < 16; ++it) {
            int idx = it * 512 + tid;
            int b = idx >> 7, gg = idx & 127;
            int g = g0 + gg;
            int q = qs[b], qa = qas[b];
            float pid = ps[b];
            tile[b][gg] = Aq[(size_t)q * G3 + g] + Bqa[(size_t)qa * G3 + g]
                        + pid * (Cqa[(size_t)qa * G3 + g] + Dq[(size_t)q * G3 + g]);
        }
        __syncthreads();
        // dense writes: per bq, 512 threads cover (gg 0..127, bl 0..3) = 2KB contiguous
        #pragma unroll
        for (int bq = 0; bq < 16; ++bq) {
            int gg = tid >> 2, bl = tid & 3;
            xgP[(((size_t)bq * LL + t) * G3 + g0 + gg) * 4 + bl] = tile[bq * 4 + bl][gg];
        }
        __syncthreads();
    }
}

// ================== persistent GRU: 16 bg x 16 ug, sentinel sync ==================
// Block (bg,ug): 4 batches x 32 units. Weights in registers (96 f32x4/lane).
// h exchange: double-buffered hU[2][64][512] via LLC; per-block slice 8KB
// (2 MB/step chip-wide). Sync: per-producer tagged sentinels; each wave polls
// only its 2 producers' sentinels (64-128B per retry). Overwrite safety: block
// finishing step t implies it observed sent>=t from ALL 16 group blocks (its 8
// waves cover ug 0..15), which certifies every consumer staged gen t-1; gen t+1
// stores (same buffer as t-1) thus never race a reader.
// lane = g*4+s: g = unit offset (0..15, two halves -> 32 units), s = k sub-slice.
__global__ __launch_bounds__(512) void gru_persist(
    const float* __restrict__ xgP,     // [16][200][1536][4]
    const float* __restrict__ w_hh,    // [1536][512]
    const float* __restrict__ b_hh,    // [1536]
    float* __restrict__ hU,            // [2][64][512]
    float* __restrict__ sent,          // [2][256] tags, stride 4 floats
    float* __restrict__ gruT2)         // [200][64][512]
{
    __shared__ float hs[8][256];          // per-wave staged h slice (4b x 64k, swizzled) 8KB
    __shared__ float part[8][3][16][8];   // wave partials [wave][gate][g][(half*4+b) rot] 12KB

    const int tid = threadIdx.x;
    const int bid = blockIdx.x;
    const int bg = bid & 15;              // batch group (4 batches)
    const int ug = bid >> 4;              // unit group
    const int j0 = ug * 32;               // first unit of this block
    const int wv = tid >> 6;              // 0..7 k-slice (64 k each)
    const int lane = tid & 63;
    const int g = lane >> 2;              // unit offset 0..15 (x2 halves)
    const int s = lane & 3;               // k sub-slice 0..3

    // ---- w_hh fragment in registers: 2 halves x 3 gates x 4 q = 96 VGPR
    f32x4 ws4[2][3][4];
    #pragma unroll
    for (int half = 0; half < 2; ++half)
        #pragma unroll
        for (int gate = 0; gate < 3; ++gate)
            #pragma unroll
            for (int q = 0; q < 4; ++q)
                ws4[half][gate][q] = *(const f32x4*)&w_hh[
                    (size_t)(gate * HH + j0 + half * 16 + g) * HH + wv * 64 + q * 16 + s * 4];

    // epilogue mapping (tid<128): b = tid>>5 (0..3), u = tid&31 (0..31)
    const int eb = tid >> 5;
    const int eu = tid & 31;
    const int ej = j0 + eu;               // global unit
    float bhr = 0.f, bhz = 0.f, bhn = 0.f;
    if (tid < 128) {
        bhr = b_hh[ej];
        bhz = b_hh[HH + ej];
        bhn = b_hh[2 * HH + ej];
    }

    // staging split: lane covers (bp = lane>>4, kc = lane&15) 16B chunk
    const int bp = lane >> 4;
    const int kc0 = lane & 15;

    const float* myxg = xgP + (size_t)bg * LL * G3 * 4;
    float* mysent_base = sent;
    const int p0 = wv * 2, p1 = wv * 2 + 1;

    for (int t = 0; t < LL; ++t) {
        // xg prefetch (cached loads; drained by the poll's vmcnt)
        float xr = 0.f, xz = 0.f, xn = 0.f;
        if (tid < 128) {
            const float* xb = myxg + (size_t)t * G3 * 4;
            xr = xb[(size_t)(0 * HH + ej) * 4 + eb];
            xz = xb[(size_t)(1 * HH + ej) * 4 + eb];
            xn = xb[(size_t)(2 * HH + ej) * 4 + eb];
        }
        // poll this wave's 2 producers' sentinels (gen t ready)
        {
            const float want = (float)t;
            const float* sb = mysent_base + ((size_t)(t & 1) * 256 + bg * 16) * 4;
            for (;;) {
                float s0, s1;
                llc_load2s(sb + p0 * 4, sb + p1 * 4, s0, s1);
                if (__all((s0 >= want) && (s1 >= want))) break;
                __builtin_amdgcn_s_sleep(1);
            }
        }
        // stage h[t&1] slice: one coherent dwordx4 per lane, swizzled LDS slot
        {
            const float* hc = hU + (size_t)(t & 1) * (64 * HH)
                            + (size_t)(bg * 4 + bp) * HH + wv * 64 + kc0 * 4;
            f32x4 v = llc_load4w(hc);
            *(f32x4*)&hs[wv][(kc0 * 4 + ((bp + kc0) & 3)) * 4] = v;
        }

        // ---- FMA: 16 ds_read_b128, 384 FMA per lane
        float acc[2][3][4] = {};
        #pragma unroll
        for (int q = 0; q < 4; ++q) {
            const int kc = q * 4 + s;
            #pragma unroll
            for (int bb = 0; bb < 4; ++bb) {
                f32x4 h4 = *(const f32x4*)&hs[wv][(kc * 4 + ((bb + kc) & 3)) * 4];
                #pragma unroll
                for (int half = 0; half < 2; ++half)
                    #pragma unroll
                    for (int gate = 0; gate < 3; ++gate)
                        acc[half][gate][bb] += ws4[half][gate][q].x * h4.x
                                             + ws4[half][gate][q].y * h4.y
                                             + ws4[half][gate][q].z * h4.z
                                             + ws4[half][gate][q].w * h4.w;
            }
        }
        // k-reduce across the 4 s-lanes of each quad (VALU DPP)
        #pragma unroll
        for (int half = 0; half < 2; ++half)
            #pragma unroll
            for (int gate = 0; gate < 3; ++gate)
                #pragma unroll
                for (int bb = 0; bb < 4; ++bb)
                    acc[half][gate][bb] = quad_sum(acc[half][gate][bb]);

        // s-lane s (<3) writes gate-s partials, rotated 8-slot rows (static idx)
        if (s < 3) {
            const int rot = (2 * ((g >> 2) + s)) & 7;
            #pragma unroll
            for (int half = 0; half < 2; ++half) {
                #pragma unroll
                for (int pp = 0; pp < 2; ++pp) {
                    const int i0 = half * 4 + pp * 2;
                    float e0, e1;
                    if (s == 0)      { e0 = acc[half][0][pp * 2]; e1 = acc[half][0][pp * 2 + 1]; }
                    else if (s == 1) { e0 = acc[half][1][pp * 2]; e1 = acc[half][1][pp * 2 + 1]; }
                    else             { e0 = acc[half][2][pp * 2]; e1 = acc[half][2][pp * 2 + 1]; }
                    const int ip = (i0 + rot) & 7;
                    *(float2*)&part[wv][s][g][ip] = make_float2(e0, e1);
                }
            }
        }
        __syncthreads();

        // ---- epilogue: 8-wave reduce + gates + tagged double-buffer store
        if (tid < 128) {
            const int gg = eu & 15, half = eu >> 4;
            float sg[3];
            #pragma unroll
            for (int gate = 0; gate < 3; ++gate) {
                const int rotg = (2 * ((gg >> 2) + gate)) & 7;
                const int idx = (half * 4 + eb + rotg) & 7;
                float ss = 0.f;
                #pragma unroll
                for (int w = 0; w < 8; ++w) ss += part[w][gate][gg][idx];
                sg[gate] = ss;
            }
            // h_prev from the staged LDS copy
            const int kch = (ej >> 2) & 15;
            float hprev = hs[ej >> 6][(kch * 4 + ((eb + kch) & 3)) * 4 + (ej & 3)];
            float rg = 1.f / (1.f + expf(-(xr + sg[0] + bhr)));
            float zg = 1.f / (1.f + expf(-(xz + sg[1] + bhz)));
            float ng = tanhf(xn + rg * (sg[2] + bhn));
            float hn = (1.f - zg) * ng + zg * hprev;
            llc_store1(hU + (size_t)((t + 1) & 1) * (64 * HH)
                          + (size_t)(bg * 4 + eb) * HH + ej, hn);
            gruT2[((size_t)t * BB + bg * 4 + eb) * HH + ej] = hn;
            // drain: h visible in LLC before sentinel release
            asm volatile("s_waitcnt vmcnt(0)" ::: "memory");
        }
        __syncthreads();   // also protects hs/part for next step
        if (tid == 0 && t + 1 < LL)
            llc_store1(mysent_base + ((size_t)((t + 1) & 1) * 256 + bg * 16 + ug) * 4,
                       (float)(t + 1));
    }
}

// -------- mvals[b,t] = threshold( dot(h_t, M2[q-1]) + mb[q-1] ) --------
__global__ __launch_bounds__(256) void mval_kernel(
    const float* __restrict__ gruT2,   // [200][64][512]
    const float* __restrict__ M2,      // [1024][512]
    const float* __restrict__ mb,
    const int* __restrict__ qint,      // [B][L]
    float* __restrict__ mval)          // [B][L]
{
    int t = blockIdx.x;
    int wave = threadIdx.x >> 6, l = threadIdx.x & 63;
    for (int ii = 0; ii < 16; ++ii) {
        int b = wave * 16 + ii;
        int q = qint[b * LL + t] - 1;
        const float4* hp = (const float4*)(gruT2 + ((size_t)t * BB + b) * HH);
        const float4* mp = (const float4*)(M2 + (size_t)q * HH);
        float4 h0 = hp[l], m0 = mp[l];
        float4 h1 = hp[64 + l], m1 = mp[64 + l];
        float acc = h0.x * m0.x + h0.y * m0.y + h0.z * m0.z + h0.w * m0.w
                  + h1.x * m1.x + h1.y * m1.y + h1.z * m1.z + h1.w * m1.w;
        acc = wave_sum64(acc);
        if (l == 0) {
            float sv = acc + mb[q];
            mval[b * LL + t] = (sv >= 0.4f) ? 1.0f : sv;
        }
    }
}

// -------- per-(b,t) counting statistics --------
__global__ __launch_bounds__(256) void stats_kernel(
    const int* __restrict__ qint, const int* __restrict__ qaint,
    const float* __restrict__ mval,
    float* __restrict__ mc, float* __restrict__ mi,
    float* __restrict__ nmc, float* __restrict__ aa)
{
    int b = blockIdx.x, tid = threadIdx.x;
    __shared__ int qs[LL];
    __shared__ int qas[LL];
    __shared__ float mv[LL];
    if (tid < LL) {
        qs[tid] = qint[b * LL + tid];
        qas[tid] = qaint[b * LL + tid];
        mv[tid] = mval[b * LL + tid];
    }
    __syncthreads();
    int t = tid;
    if (t < LL) {
        int qt = qs[t];
        float smc = 0.f, smi = 0.f, snmc = 0.f, saa = 0.f;
        for (int k = 0; k <= t; ++k) {
            if (qs[k] == qt) {
                saa += 1.f;
                if (k < t) {
                    float mk = (mv[k] == 1.f) ? 1.f : 0.f;
                    float nk = (mv[k] == 0.f) ? 1.f : 0.f;
                    float a1 = (qas[k] == 1) ? 1.f : 0.f;
                    smc += a1 * mk;
                    smi += (1.f - a1) * mk;
                    snmc += (1.f - a1) * nk;
                }
            }
        }
        mc[b * LL + t] = smc;
        mi[b * LL + t] = smi;
        nmc[b * LL + t] = snmc;
        aa[b * LL + t] = saa;
    }
}

// -------- sequential DINA scan per batch --------
__global__ __launch_bounds__(256) void dina_kernel(
    const int* __restrict__ qint, const int* __restrict__ qaint,
    const float* __restrict__ mval,
    const float* __restrict__ mc, const float* __restrict__ mi,
    const float* __restrict__ nmc, const float* __restrict__ aa,
    float* __restrict__ preds)
{
    int b = blockIdx.x, tid = threadIdx.x;
    __shared__ float guess[QQ], slip[QQ];
    __shared__ float s_m[LL], s_mc[LL], s_mi[LL], s_nmc[LL], s_aa[LL];
    __shared__ int s_i[LL], s_qa[LL];
    for (int i = tid; i < QQ; i += 256) { guess[i] = 0.f; slip[i] = 0.f; }
    if (tid < LL) {
        s_m[tid] = mval[b * LL + tid];
        s_mc[tid] = mc[b * LL + tid];
        s_mi[tid] = mi[b * LL + tid];
        s_nmc[tid] = nmc[b * LL + tid];
        s_aa[tid] = aa[b * LL + tid];
        s_i[tid] = qint[b * LL + tid] - 1;
        s_qa[tid] = qaint[b * LL + tid];
    }
    __syncthreads();
    if (tid == 0) {
        for (int t = 0; t < LL; ++t) {
            int i = s_i[t];
            float m = s_m[t];
            int qa = s_qa[t];
            float aat = s_aa[t];
            float g_upd = (m == 1.f) ? s_mc[t] / aat
                          : ((qa == 0) ? 1.f - s_nmc[t] / aat : s_nmc[t] / aat);
            bool us = (m == 1.f) && (qa == 0);
            float ng = us ? guess[i] : g_upd;
            float ns = us ? s_mi[t] / aat : slip[i];
            guess[i] = ng;
            slip[i] = ns;
            preds[b * LL + t] = (1.f - ns) * (m * ng + (1.f - ns) * (1.f - m));
        }
    }
}

// -------- masked MSE + sigmoid outputs --------
__global__ __launch_bounds__(256) void loss_kernel(
    const float* __restrict__ preds, const float* __restrict__ target,
    float* __restrict__ out, float* __restrict__ acc)
{
    int r = blockIdx.x * 256 + threadIdx.x;
    float lm = 0.f, lc = 0.f;
    if (r < BL) {
        float p = preds[r], lab = target[r];
        float msk = (lab > -0.9f) ? 1.f : 0.f;
        float d = p - lab;
        lm = d * d * msk;
        lc = msk;
        out[1 + r] = 1.f / (1.f + expf(-p));
    }
    lm = wave_sum64(lm);
    lc = wave_sum64(lc);
    __shared__ float sm[4], sc[4];
    int lane = threadIdx.x & 63, w = threadIdx.x >> 6;
    if (lane == 0) { sm[w] = lm; sc[w] = lc; }
    __syncthreads();
    if (threadIdx.x == 0) {
        atomicAdd(&acc[1], sm[0] + sm[1] + sm[2] + sm[3]);
        atomicAdd(&acc[2], sc[0] + sc[1] + sc[2] + sc[3]);
    }
}

__global__ void final_kernel(const float* __restrict__ acc, float* __restrict__ out)
{
    out[0] = acc[1] + acc[0] * 1e-5f;
    out[1 + BL] = acc[2];
}

extern "C" void kernel_launch(void* const* d_in, const int* in_sizes, int n_in,
                              void* d_out, int out_size, void* d_ws, size_t ws_size,
                              hipStream_t stream) {
    const int* q_data = (const int*)d_in[0];
    const int* qa_data = (const int*)d_in[1];
    const int* pid_data = (const int*)d_in[2];
    const float* matrix = (const float*)d_in[3];
    const float* target = (const float*)d_in[4];
    const float* q_emb = (const float*)d_in[5];
    const float* qa_emb = (const float*)d_in[6];
    const float* q_emb_diff = (const float*)d_in[7];
    const float* qa_emb_diff = (const float*)d_in[8];
    const float* diff_parm = (const float*)d_in[9];
    const float* w_ih = (const float*)d_in[10];
    const float* w_hh = (const float*)d_in[11];
    const float* b_ih = (const float*)d_in[12];
    const float* b_hh = (const float*)d_in[13];
    const float* fc_w = (const float*)d_in[14];
    const float* fc_b = (const float*)d_in[15];
    float* out = (float*)d_out;
    float* W = (float*)d_ws;

    float* acc = W + OFF_ACC;
    float* Aq = W + OFF_AQ;
    float* Dq = W + OFF_DQ;
    float* Bqa = W + OFF_BQA;
    float* Cqa = W + OFF_CQA;
    float* wsum = W + OFF_WSUM;
    float* fcwT = W + OFF_FCWT;
    float* M2 = W + OFF_M2;
    float* mb = W + OFF_MB;
    float* xgP = W + OFF_XG;
    float* m2parts = W + OFF_XG;       // temp: reused before xgP is written
    float* gruT2 = W + OFF_GRUT;
    int* qint = (int*)(W + OFF_QINT);
    int* qaint = (int*)(W + OFF_QAINT);
    float* pidf = W + OFF_PIDF;
    float* mval = W + OFF_MVAL;
    float* mc = W + OFF_MC;
    float* mi = W + OFF_MI;
    float* nmc = W + OFF_NMC;
    float* aa = W + OFF_AA;
    float* preds = W + OFF_PREDS;

    // hU (2*64*512) + sentinels (2*256*4) alias the Aq region (dead after xgt)
    float* hU = W + OFF_AQ;
    float* sent = hU + 2 * 64 * HH;

    // zero accumulators
    hipMemsetAsync(W, 0, 1056 * sizeof(float), stream);

    prep_meta<<<50, 256, 0, stream>>>(q_data, qa_data, pid_data, diff_parm,
                                      qint, qaint, pidf, acc);
    wsum_kernel<<<G3, 256, 0, stream>>>(w_ih, wsum);
    transpose_kernel<<<dim3(16, 32), 256, 0, stream>>>(fc_w, fcwT, QQ, HH);

    // Bqa/Cqa batched
    gemm_nt_dual<<<dim3(24, 1, 2), 256, 0, stream>>>(
        qa_emb, qa_emb_diff, DD, w_ih, w_ih, 2 * DD, 2 * DD,
        Bqa, Cqa, G3, 2, G3, DD, b_ih, nullptr);
    // Aq/Dq batched
    gemm_nt_dual<<<dim3(24, 17, 2), 256, 0, stream>>>(
        q_emb, q_emb_diff, DD, wsum, w_ih + DD, DD, 2 * DD,
        Aq, Dq, G3, NQ + 1, G3, DD, nullptr, nullptr);
    // M2 = matrix . fc_w  (split-K x4 into temp region, then reduce)
    gemm_nt_splitk<<<dim3(8, 16, 4), 256, 0, stream>>>(
        matrix, QQ, fcwT, QQ, m2parts, HH, QQ, HH, QQ / 4);
    reduce4_kernel<<<2048, 256, 0, stream>>>(m2parts, M2, QQ * HH);
    mb_kernel<<<QQ, 256, 0, stream>>>(matrix, fc_b, mb);

    // xg gather+transpose into xgP (overwrites the m2parts temp region)
    xgt_kernel<<<LL, 512, 0, stream>>>(Aq, Bqa, Cqa, Dq, qint, qaint, pidf, xgP);

    // zero h double-buffer + sentinels (Aq now dead; stream-ordered after xgt)
    hipMemsetAsync(hU, 0, (2 * 64 * HH + 2 * 256 * 4) * sizeof(float), stream);

    gru_persist<<<GBLK, 512, 0, stream>>>(xgP, w_hh, b_hh, hU, sent, gruT2);

    mval_kernel<<<LL, 256, 0, stream>>>(gruT2, M2, mb, qint, mval);
    stats_kernel<<<BB, 256, 0, stream>>>(qint, qaint, mval, mc, mi, nmc, aa);
    dina_kernel<<<BB, 256, 0, stream>>>(qint, qaint, mval, mc, mi, nmc, aa, preds);
    loss_kernel<<<50, 256, 0, stream>>>(preds, target, out, acc);
    final_kernel<<<1, 1, 0, stream>>>(acc, out);
}